// Round 2
// baseline (240.216 us; speedup 1.0000x reference)
//
#include <hip/hip_runtime.h>

// RotatedGridPool: B=4, C=256, H=200, W=176, N=128, G=7
// Output: (B*N, C, G, G) fp32.
//
// R5: LDS patch staging. The 49 sample points of one ROI live in a patch of
// at most ~16x16 px (span = (dx|cos|+dy|sin|)/0.4 * 6/7 <= 13.7 px, plus
// floor/bilinear corners; PDIM=18 adds 1px safety each side for fp rounding).
// Instead of 2 divergent dwordx2 gathers per output (12.8M scattered lane
// requests, ~45% cache-line utilization), each block:
//   1. computes the ROI's patch bbox (all threads, redundant),
//   2. stages CCHUNK=16 channel patches into LDS with coalesced row loads
//      (exact footprint, full line utilization),
//   3. serves all 784 bilinear samples from LDS (2x ds_read2_b32 each).
// Keeps R4's XCD-aware decode (L2 working set ~2 groups/XCD) and
// non-temporal output stores.

constexpr int Bc = 4;
constexpr int Cc = 256;
constexpr int Hc = 200;
constexpr int Wc = 176;
constexpr int Nc = 128;
constexpr int G  = 7;
constexpr int NPTS = G * G;           // 49
constexpr int CSPLIT = 16;            // blocks per ROI (channel splits)
constexpr int CCHUNK = Cc / CSPLIT;   // 16 channels per block
constexpr int ELEMS  = CCHUNK * NPTS; // 784
constexpr int NXCD = 8;
constexpr int HWc = Hc * Wc;
constexpr int PDIM = 18;              // patch dim: <=16 needed + 2 safety
constexpr int CSTR = PDIM * PDIM;     // 324 floats per channel patch
constexpr float MIN_Xf = 0.0f;
constexpr float MIN_Yf = -40.0f;

__global__ __launch_bounds__(256, 7) void rot_grid_pool_kernel(
    const float* __restrict__ feat,       // (B,C,H,W)
    const float* __restrict__ rois,       // (B,N,7)
    const float* __restrict__ voxel_size, // (2,)
    const int*   __restrict__ fms,        // scalar stride
    float* __restrict__ out)              // (B*N, C, G, G)
{
    // ---- XCD-aware decode (R4): block g -> XCD g%8; each XCD walks
    // (b,chunk) groups sequentially, 128 ROI-blocks per group. ----
    const int g     = blockIdx.x;
    const int xcd   = g & (NXCD - 1);
    const int s     = g >> 3;
    const int group = s >> 7;             // 0..7
    const int roi   = s & 127;            // 0..127
    const int pair  = group * NXCD + xcd; // 0..63  == b*CSPLIT + chunk
    const int b     = pair >> 4;
    const int chunk = pair & (CSPLIT - 1);
    const int bn    = (b << 7) | roi;

    __shared__ float  s_patch[CCHUNK * CSTR]; // 20736 B
    __shared__ int2   s_off[NPTS];            // patch-relative row offsets
    __shared__ float4 s_wgt[NPTS];            // weights for the 4 corners

    const int tid = threadIdx.x;

    // ---- per-ROI affine theta: computed redundantly on all threads ----
    const float* roi_p = rois + (size_t)bn * 7;
    const float cx = roi_p[0], cy = roi_p[1];
    const float dx = roi_p[3], dy = roi_p[4];
    const float ang = roi_p[6];
    const float stride = (float)fms[0];
    const float vx = voxel_size[0] * stride;
    const float vy = voxel_size[1] * stride;

    const float x1 = (cx - dx * 0.5f - MIN_Xf) / vx;
    const float x2 = (cx + dx * 0.5f - MIN_Xf) / vx;
    const float y1 = (cy - dy * 0.5f - MIN_Yf) / vy;
    const float y2 = (cy + dy * 0.5f - MIN_Yf) / vy;

    float sina, cosa;
    __sincosf(ang, &sina, &cosa);

    const float wm1 = (float)(Wc - 1);
    const float hm1 = (float)(Hc - 1);
    const float scale1 = (y2 - y1) / fmaxf(x2 - x1, 0.01f);
    const float scale2 = (x2 - x1) / fmaxf(y2 - y1, 0.01f);
    const float t00 = (x2 - x1) / wm1 * cosa;
    const float t01 = (x2 - x1) / wm1 * (-sina) * scale1;
    const float t02 = (x1 + x2 - wm1) / wm1;
    const float t10 = (y2 - y1) / hm1 * sina * scale2;
    const float t11 = (y2 - y1) / hm1 * cosa;
    const float t12 = (y1 + y2 - hm1) / hm1;

    // ---- patch bbox: affine extremes are at grid corners (xx,yy = +-6/7);
    // widen by 1 px each side against fp rounding differences vs per-point ----
    const float ext = 6.0f / 7.0f;
    const float sx = (fabsf(t00) + fabsf(t01)) * ext;
    const float sy = (fabsf(t10) + fabsf(t11)) * ext;
    const float ixmin = ((t02 - sx + 1.0f) * (float)Wc - 1.0f) * 0.5f;
    const float ixmax = ((t02 + sx + 1.0f) * (float)Wc - 1.0f) * 0.5f;
    const float iymin = ((t12 - sy + 1.0f) * (float)Hc - 1.0f) * 0.5f;
    const float iymax = ((t12 + sy + 1.0f) * (float)Hc - 1.0f) * 0.5f;
    const int xlo = min(max((int)floorf(ixmin) - 1, 0), Wc - 2);
    const int xhi = min(max((int)floorf(ixmax) + 2, 1), Wc - 1);
    const int ylo = min(max((int)floorf(iymin) - 1, 0), Hc - 1);
    const int yhi = min(max((int)floorf(iymax) + 2, 1), Hc - 1);
    const int pw = min(xhi - xlo + 1, PDIM);
    const int ph = min(yhi - ylo + 1, PDIM);

    if (tid < NPTS) {
        const int row = tid / G;
        const int col = tid - row * G;
        const float xx = (2.0f * (float)col + 1.0f) / (float)G - 1.0f;
        const float yy = (2.0f * (float)row + 1.0f) / (float)G - 1.0f;
        const float gx = t00 * xx + t01 * yy + t02;
        const float gy = t10 * xx + t11 * yy + t12;
        const float ix = ((gx + 1.0f) * (float)Wc - 1.0f) * 0.5f;
        const float iy = ((gy + 1.0f) * (float)Hc - 1.0f) * 0.5f;

        const float x0f = floorf(ix);
        const float y0f = floorf(iy);
        const float wx1 = ix - x0f, wx0 = 1.0f - wx1;
        const float wy1 = iy - y0f, wy0 = 1.0f - wy1;

        const bool vx0 = (x0f >= 0.0f) && (x0f <= wm1);
        const bool vx1 = (x0f + 1.0f >= 0.0f) && (x0f + 1.0f <= wm1);
        const bool vy0 = (y0f >= 0.0f) && (y0f <= hm1);
        const bool vy1 = (y0f + 1.0f >= 0.0f) && (y0f + 1.0f <= hm1);

        const int x0i = (int)x0f;
        const int y0i = (int)y0f;
        const int xs  = min(max(x0i, 0), Wc - 2);   // pair at xs always in-bounds
        const int yc0 = min(max(y0i, 0), Hc - 1);
        const int yc1 = min(max(y0i + 1, 0), Hc - 1);

        // weights applying to f[xs] (wa) and f[xs+1] (wb), edge cases folded in
        const float wa = ((vx0 && x0i     == xs    ) ? wx0 : 0.0f)
                       + ((vx1 && x0i + 1 == xs    ) ? wx1 : 0.0f);
        const float wb = ((vx0 && x0i     == xs + 1) ? wx0 : 0.0f)
                       + ((vx1 && x0i + 1 == xs + 1) ? wx1 : 0.0f);
        const float rw0 = vy0 ? wy0 : 0.0f;
        const float rw1 = vy1 ? wy1 : 0.0f;

        // patch-relative offsets (bbox covers clamped coords by construction)
        s_off[tid] = make_int2((yc0 - ylo) * PDIM + (xs - xlo),
                               (yc1 - ylo) * PDIM + (xs - xlo));
        s_wgt[tid] = make_float4(rw0 * wa, rw0 * wb, rw1 * wa, rw1 * wb);
    }

    // ---- stage patch: coalesced row loads, exact footprint ----
    const float* __restrict__ fb = feat + ((size_t)b * Cc + chunk * CCHUNK) * HWc;
    #pragma unroll 4
    for (int i = tid; i < CCHUNK * CSTR; i += 256) {
        const int c  = i / CSTR;           // const-div -> magic mul
        const int r  = i - c * CSTR;
        const int py = r / PDIM;
        const int px = r - py * PDIM;
        if (py < ph && px < pw)
            s_patch[i] = fb[(size_t)c * HWc + (ylo + py) * Wc + (xlo + px)];
    }
    __syncthreads();

    // ---- sample from LDS ----
    float* __restrict__ ob = out + ((size_t)bn * Cc + chunk * CCHUNK) * NPTS;
    #pragma unroll
    for (int k = 0; k < 4; ++k) {
        const int e = tid + k * 256;
        if (e < ELEMS) {
            const int c  = e / NPTS;
            const int pt = e - c * NPTS;
            const float* __restrict__ pc = s_patch + c * CSTR;
            const int2   o = s_off[pt];
            const float4 w = s_wgt[pt];
            const float v = w.x * pc[o.x] + w.y * pc[o.x + 1]
                          + w.z * pc[o.y] + w.w * pc[o.y + 1];
            __builtin_nontemporal_store(v, ob + e);
        }
    }
}

extern "C" void kernel_launch(void* const* d_in, const int* in_sizes, int n_in,
                              void* d_out, int out_size, void* d_ws, size_t ws_size,
                              hipStream_t stream) {
    const float* feat = (const float*)d_in[0];
    const float* rois = (const float*)d_in[1];
    const float* vox  = (const float*)d_in[2];
    const int*   fms  = (const int*)d_in[3];
    float* out = (float*)d_out;

    rot_grid_pool_kernel<<<dim3(Bc * Nc * CSPLIT), dim3(256), 0, stream>>>(
        feat, rois, vox, fms, out);
}

// Round 3
// 209.875 us; speedup vs baseline: 1.1446x; 1.1446x over previous
//
#include <hip/hip_runtime.h>

// RotatedGridPool: B=4, C=256, H=200, W=176, N=128, G=7
// Output: (B*N, C, G, G) fp32.
//
// R6: revert to the R4 gather structure (measured best, kernel ~36us; the R5
// LDS bbox staging regressed to ~68us because the per-ROI channel blocks read
// DISJOINT channels -> no redundancy to eliminate, and L1 already served
// intra-patch reuse). Remove the remaining per-element overhead instead:
//  - R4 re-read s_off (int2, ~3-way LDS bank conflict) and s_wgt (float4,
//    ds_read_b128 at pt*16B = ~8-way conflict) every k-iteration, plus a
//    magic-div. R6 has NO LDS at all: thread t<245 owns pt = t%49 and
//    cb = t/49, computes theta (uniform -> scalarized) + its own bilinear
//    setup in registers once, then loops channels c = cb, cb+5, ... with
//    pointer increments only.
//  - Stores stay fully coalesced: out index = t + 245*k.
//  - Keeps R4's XCD-aware decode (CSPLIT=16 -> 2.25MB group footprint/XCD)
//    and non-temporal output stores.
// Gathers themselves unchanged: 2 x dwordx2 per element, always in-bounds,
// zero-padding folded into 4 precomputed corner weights.

constexpr int Bc = 4;
constexpr int Cc = 256;
constexpr int Hc = 200;
constexpr int Wc = 176;
constexpr int Nc = 128;
constexpr int G  = 7;
constexpr int NPTS = G * G;           // 49
constexpr int CSPLIT = 16;            // blocks per ROI (channel splits)
constexpr int CCHUNK = Cc / CSPLIT;   // 16 channels per block
constexpr int NXCD = 8;
constexpr int HWc = Hc * Wc;
constexpr int NACT = 5 * NPTS;        // 245 active threads
constexpr float MIN_Xf = 0.0f;
constexpr float MIN_Yf = -40.0f;

// 8-byte load with only 4-byte alignment guarantee (x-offset is arbitrary).
struct __attribute__((packed, aligned(4))) f2u { float x, y; };

__global__ __launch_bounds__(256, 8) void rot_grid_pool_kernel(
    const float* __restrict__ feat,       // (B,C,H,W)
    const float* __restrict__ rois,       // (B,N,7)
    const float* __restrict__ voxel_size, // (2,)
    const int*   __restrict__ fms,        // scalar stride
    float* __restrict__ out)              // (B*N, C, G, G)
{
    // ---- XCD-aware decode (R4): block g -> XCD g%8; each XCD walks
    // (b,chunk) groups sequentially, 128 ROI-blocks per group. ----
    const int g     = blockIdx.x;
    const int xcd   = g & (NXCD - 1);
    const int s     = g >> 3;
    const int group = s >> 7;             // 0..7
    const int roi   = s & 127;            // 0..127
    const int pair  = group * NXCD + xcd; // 0..63  == b*CSPLIT + chunk
    const int b     = pair >> 4;
    const int chunk = pair & (CSPLIT - 1);
    const int bn    = (b << 7) | roi;

    const int t = threadIdx.x;
    if (t >= NACT) return;                // 11 masked lanes in wave 3
    const int cb = t / NPTS;              // 0..4 (magic mul)
    const int pt = t - cb * NPTS;         // 0..48

    // ---- per-ROI affine theta (block-uniform -> compiler scalarizes) ----
    const float* roi_p = rois + (size_t)bn * 7;
    const float cx = roi_p[0], cy = roi_p[1];
    const float dx = roi_p[3], dy = roi_p[4];
    const float ang = roi_p[6];
    const float stride = (float)fms[0];
    const float vx = voxel_size[0] * stride;
    const float vy = voxel_size[1] * stride;

    const float x1 = (cx - dx * 0.5f - MIN_Xf) / vx;
    const float x2 = (cx + dx * 0.5f - MIN_Xf) / vx;
    const float y1 = (cy - dy * 0.5f - MIN_Yf) / vy;
    const float y2 = (cy + dy * 0.5f - MIN_Yf) / vy;

    float sina, cosa;
    __sincosf(ang, &sina, &cosa);

    const float wm1 = (float)(Wc - 1);
    const float hm1 = (float)(Hc - 1);
    const float scale1 = (y2 - y1) / fmaxf(x2 - x1, 0.01f);
    const float scale2 = (x2 - x1) / fmaxf(y2 - y1, 0.01f);
    const float t00 = (x2 - x1) / wm1 * cosa;
    const float t01 = (x2 - x1) / wm1 * (-sina) * scale1;
    const float t02 = (x1 + x2 - wm1) / wm1;
    const float t10 = (y2 - y1) / hm1 * sina * scale2;
    const float t11 = (y2 - y1) / hm1 * cosa;
    const float t12 = (y1 + y2 - hm1) / hm1;

    // ---- this thread's sample point: bilinear setup in registers ----
    const int row = pt / G;
    const int col = pt - row * G;
    const float xx = (2.0f * (float)col + 1.0f) / (float)G - 1.0f;
    const float yy = (2.0f * (float)row + 1.0f) / (float)G - 1.0f;
    const float gx = t00 * xx + t01 * yy + t02;
    const float gy = t10 * xx + t11 * yy + t12;
    const float ix = ((gx + 1.0f) * (float)Wc - 1.0f) * 0.5f;
    const float iy = ((gy + 1.0f) * (float)Hc - 1.0f) * 0.5f;

    const float x0f = floorf(ix);
    const float y0f = floorf(iy);
    const float wx1 = ix - x0f, wx0 = 1.0f - wx1;
    const float wy1 = iy - y0f, wy0 = 1.0f - wy1;

    const bool vx0 = (x0f >= 0.0f) && (x0f <= wm1);
    const bool vx1 = (x0f + 1.0f >= 0.0f) && (x0f + 1.0f <= wm1);
    const bool vy0 = (y0f >= 0.0f) && (y0f <= hm1);
    const bool vy1 = (y0f + 1.0f >= 0.0f) && (y0f + 1.0f <= hm1);

    const int x0i = (int)x0f;
    const int y0i = (int)y0f;
    const int xs  = min(max(x0i, 0), Wc - 2);   // dwordx2 at xs always in-bounds
    const int yc0 = min(max(y0i, 0), Hc - 1);
    const int yc1 = min(max(y0i + 1, 0), Hc - 1);

    // weights applying to f[xs] (wa) and f[xs+1] (wb), edge cases folded in
    const float wa = ((vx0 && x0i     == xs    ) ? wx0 : 0.0f)
                   + ((vx1 && x0i + 1 == xs    ) ? wx1 : 0.0f);
    const float wb = ((vx0 && x0i     == xs + 1) ? wx0 : 0.0f)
                   + ((vx1 && x0i + 1 == xs + 1) ? wx1 : 0.0f);
    const float rw0 = vy0 ? wy0 : 0.0f;
    const float rw1 = vy1 ? wy1 : 0.0f;
    const float w0 = rw0 * wa, w1 = rw0 * wb;
    const float w2 = rw1 * wa, w3 = rw1 * wb;

    // ---- channel loop: c = cb, cb+5, ... ; pointer increments only ----
    const float* __restrict__ fb =
        feat + ((size_t)b * Cc + chunk * CCHUNK) * HWc;
    const float* p0 = fb + (size_t)cb * HWc + (yc0 * Wc + xs);
    const float* p1 = fb + (size_t)cb * HWc + (yc1 * Wc + xs);
    float* obp = out + ((size_t)bn * Cc + chunk * CCHUNK) * NPTS + t;

    for (int c = cb; c < CCHUNK; c += 5) {
        const f2u r0 = *(const f2u*)p0;
        const f2u r1 = *(const f2u*)p1;
        const float v = w0 * r0.x + w1 * r0.y + w2 * r1.x + w3 * r1.y;
        __builtin_nontemporal_store(v, obp);
        p0 += 5 * HWc;
        p1 += 5 * HWc;
        obp += NACT;
    }
}

extern "C" void kernel_launch(void* const* d_in, const int* in_sizes, int n_in,
                              void* d_out, int out_size, void* d_ws, size_t ws_size,
                              hipStream_t stream) {
    const float* feat = (const float*)d_in[0];
    const float* rois = (const float*)d_in[1];
    const float* vox  = (const float*)d_in[2];
    const int*   fms  = (const int*)d_in[3];
    float* out = (float*)d_out;

    rot_grid_pool_kernel<<<dim3(Bc * Nc * CSPLIT), dim3(256), 0, stream>>>(
        feat, rois, vox, fms, out);
}